// Round 7
// baseline (704.787 us; speedup 1.0000x reference)
//
#include <hip/hip_runtime.h>
#include <cstdint>
#include <cstddef>

typedef __bf16          bf16x8  __attribute__((ext_vector_type(8)));
typedef float           f32x4   __attribute__((ext_vector_type(4)));
typedef unsigned short  u16x8   __attribute__((ext_vector_type(8)));

__device__ __forceinline__ unsigned short f32_bf16_rne(float f) {
  union { float f; unsigned u; } v; v.f = f;
  unsigned u = v.u + 0x7FFFu + ((v.u >> 16) & 1u);
  return (unsigned short)(u >> 16);
}

// ---------------- flat fp32 -> bf16 convert (vectorized, G13) ----------------
__global__ void cvt_f32_bf16(const float* __restrict__ in,
                             unsigned short* __restrict__ out, int n8) {
  int idx = blockIdx.x * 256 + threadIdx.x;
  int stride = gridDim.x * 256;
  for (int i = idx; i < n8; i += stride) {
    float4 a = ((const float4*)in)[2 * (size_t)i];
    float4 b = ((const float4*)in)[2 * (size_t)i + 1];
    u16x8 o;
    o[0] = f32_bf16_rne(a.x); o[1] = f32_bf16_rne(a.y);
    o[2] = f32_bf16_rne(a.z); o[3] = f32_bf16_rne(a.w);
    o[4] = f32_bf16_rne(b.x); o[5] = f32_bf16_rne(b.y);
    o[6] = f32_bf16_rne(b.z); o[7] = f32_bf16_rne(b.w);
    *(u16x8*)(out + (size_t)i * 8) = o;
  }
}

// ------------- beta (H x O, f32) -> betaT (O x H, bf16) transpose ------------
__global__ void cvt_transpose(const float* __restrict__ in,
                              unsigned short* __restrict__ out, int H, int O) {
  __shared__ float tile[32][33];
  int o0 = blockIdx.x * 32, h0 = blockIdx.y * 32;
  int tx = threadIdx.x & 31, ty = threadIdx.x >> 5;
  #pragma unroll
  for (int i = ty; i < 32; i += 8)
    tile[i][tx] = in[(size_t)(h0 + i) * O + (o0 + tx)];
  __syncthreads();
  #pragma unroll
  for (int i = ty; i < 32; i += 8)
    out[(size_t)(o0 + i) * H + (h0 + tx)] = f32_bf16_rne(tile[tx][i]);
}

#define GLOAD(gp, lp)                                                   \
  __builtin_amdgcn_global_load_lds(                                     \
      (const __attribute__((address_space(1))) void*)(gp),              \
      (__attribute__((address_space(3))) void*)(lp), 16, 0, 0)

#define MFMA16 __builtin_amdgcn_mfma_f32_16x16x32_bf16

__device__ __forceinline__ void mfma32(f32x4 (&acc)[4][4],
                                       const bf16x8 (&fa)[2][4],
                                       const bf16x8 (&fb)[2][4]) {
  #pragma unroll
  for (int kk = 0; kk < 2; ++kk)
    #pragma unroll
    for (int m = 0; m < 4; ++m)
      #pragma unroll
      for (int n = 0; n < 4; ++n)
        acc[m][n] = MFMA16(fa[kk][m], fb[kk][n], acc[m][n], 0, 0, 0);
}

// ============ 128x256 8-wave GEMM: A reg-staged in LDS, B direct from L2 =====
// C[m,n] = relu(scale * sum_k A[m,k]*B[n,k]) -> bf16.   A: MxK, B: NxK bf16.
// Waves 2M x 4N, per-wave 64x64.  LDS: ONLY A, 2 slots x 16 KiB (dbuf).
// B frags load straight from global (W panel is L2-resident, XCD-pinned by
// gridDim.x==8).  Per K-tile LDS pipe: 64 ds_read_b128 + 16KB ds_write
// (~960cy) < MFMA 1240cy  (R3's all-LDS version: 192 reads ~ 2300cy, bound).
//
// NO hand-counted vmcnt: A-stage is global_load->VGPR->ds_write (T14), so all
// waits are compiler-derived register deps.  Only inline asm: lgkmcnt(0)
// before the raw s_barrier (keeps B(t+1)/A(t+2) prefetches in flight across
// the barrier — no vmcnt(0) drain).
// Hazards per body t:  RAW on slot cur: ds_write(t) done (lgkm0) + barrier at
// end of body t-1.  WAR on slot nxt: its old tile t-1 frags were lgkm-waited
// before MFMA(t-1), hence done before every wave crossed barrier(t-1); our
// ds_write(t+1) comes after that barrier.  Register WAR/RAW: compiler.

#define BODYR(T, SCUR, SNXT, BCUR, BNXT, AR0, AR1, AW0, AW1)              \
  do {                                                                    \
    const int t_ = (T);                                                   \
    bf16x8 fa[2][4];                                                      \
    {                                                                     \
      const __bf16* rA = As + (SCUR) * 8192;                              \
      _Pragma("unroll")                                                   \
      for (int m = 0; m < 4; ++m) {                                       \
        fa[0][m] = *(const bf16x8*)(rA + (aRow + m * 16) * 64 + cc0);     \
        fa[1][m] = *(const bf16x8*)(rA + (aRow + m * 16) * 64 + cc1);     \
      }                                                                   \
    }                                                                     \
    if (t_ + 1 < NT) {                                                    \
      const size_t bko = (size_t)(t_ + 1) * 64;                           \
      _Pragma("unroll")                                                   \
      for (int n = 0; n < 4; ++n) {                                       \
        BNXT[0][n] = *(const bf16x8*)(gB + n * bstride + bko);            \
        BNXT[1][n] = *(const bf16x8*)(gB + n * bstride + bko + 32);       \
      }                                                                   \
    }                                                                     \
    if (t_ + 2 < NT) {                                                    \
      const size_t ako = (size_t)(t_ + 2) * 64;                           \
      AR0 = *(const bf16x8*)(gA0 + ako);                                  \
      AR1 = *(const bf16x8*)(gA1 + ako);                                  \
    }                                                                     \
    __builtin_amdgcn_s_setprio(1);                                        \
    mfma32(acc, fa, BCUR);                                                \
    __builtin_amdgcn_s_setprio(0);                                        \
    if (t_ + 1 < NT) {                                                    \
      __bf16* wA = As + (SNXT) * 8192;                                    \
      *(bf16x8*)(wA + wOff0) = AW0;                                       \
      *(bf16x8*)(wA + wOff1) = AW1;                                       \
    }                                                                     \
    asm volatile("s_waitcnt lgkmcnt(0)" ::: "memory");                    \
    __builtin_amdgcn_s_barrier();                                         \
    __builtin_amdgcn_sched_barrier(0);                                    \
  } while (0)

__global__ __launch_bounds__(512, 2)
void gemm128x256r(const unsigned short* __restrict__ A,
                  const unsigned short* __restrict__ B,
                  unsigned short* __restrict__ Cp, int N, int K, float scale) {
  __shared__ __bf16 As[2 * 128 * 64] __attribute__((aligned(16)));  // 32 KiB

  const int tid  = threadIdx.x;
  const int lane = tid & 63;
  const int wave = tid >> 6;      // 0..7
  const int wr   = wave >> 2;     // 0..1 (M)
  const int wc   = wave & 3;      // 0..3 (N)
  const int l16  = lane & 15;
  const int kgrp = lane >> 4;     // 0..3

  const int brow0 = blockIdx.y * 128;
  const int bcol0 = blockIdx.x * 256;   // gridDim.x = 8 = #XCDs

  // A ds_read addressing (T2 swizzle): elem = row*64 + (col ^ ((row&7)<<3))
  const int xorv = (l16 & 7) << 3;
  const int cc0  = (kgrp * 8) ^ xorv;
  const int cc1  = (32 + kgrp * 8) ^ xorv;
  const int aRow = wr * 64 + l16;

  // A staging: thread loads rows {srow, srow+64}, 8 elems at scolL (linear,
  // coalesced); ds_write applies the same XOR swizzle the reads expect.
  const int srow  = tid >> 3;                    // 0..63
  const int scolL = (tid & 7) * 8;               // linear col
  const int wOff0 = srow * 64 + (scolL ^ ((srow & 7) << 3));
  const int wOff1 = wOff0 + 64 * 64;             // (srow+64)&7 == srow&7
  const unsigned short* gA0u = A + (size_t)(brow0 +  0 + srow) * K + scolL;
  const unsigned short* gA1u = A + (size_t)(brow0 + 64 + srow) * K + scolL;
  const __bf16* gA0 = (const __bf16*)gA0u;
  const __bf16* gA1 = (const __bf16*)gA1u;

  // B direct: lane reads row (bcol0 + wc*64 + n*16 + l16), elems kgrp*8 (+32)
  const __bf16* gB = (const __bf16*)B +
                     (size_t)(bcol0 + wc * 64 + l16) * K + kgrp * 8;
  const size_t bstride = (size_t)16 * K;  // n-fragment row stride

  f32x4  acc[4][4] = {};
  bf16x8 bE[2][4], bO[2][4];
  bf16x8 aE0, aE1, aO0, aO1;

  const int NT = K >> 6;  // 32 for K=2048 (assumes NT even, >= 2)

  // ---- prologue: load A(0),A(1),B(0); write A(0) -> slot 0
  aE0 = *(const bf16x8*)(gA0);
  aE1 = *(const bf16x8*)(gA1);
  aO0 = *(const bf16x8*)(gA0 + 64);
  aO1 = *(const bf16x8*)(gA1 + 64);
  #pragma unroll
  for (int n = 0; n < 4; ++n) {
    bE[0][n] = *(const bf16x8*)(gB + n * bstride);
    bE[1][n] = *(const bf16x8*)(gB + n * bstride + 32);
  }
  *(bf16x8*)(As + wOff0) = aE0;   // compiler inserts vmcnt wait for aE0/aE1
  *(bf16x8*)(As + wOff1) = aE1;
  asm volatile("s_waitcnt lgkmcnt(0)" ::: "memory");
  __builtin_amdgcn_s_barrier();
  __builtin_amdgcn_sched_barrier(0);

  // body even t: read slot0, MFMA bE; write A(t+1)=aO -> slot1; reload aE
  // body odd  t: read slot1, MFMA bO; write A(t+1)=aE -> slot0; reload aO
  for (int t = 0; t < NT; t += 2) {
    BODYR(t,     0, 1, bE, bO, aE0, aE1, aO0, aO1);
    BODYR(t + 1, 1, 0, bO, bE, aO0, aO1, aE0, aE1);
  }

  // epilogue: relu(acc*scale) -> bf16. D: col=lane&15, row=(lane>>4)*4+j
  const int crow0 = brow0 + wr * 64 + kgrp * 4;
  const int ccol0 = bcol0 + wc * 64 + l16;
  #pragma unroll
  for (int m = 0; m < 4; ++m)
    #pragma unroll
    for (int n = 0; n < 4; ++n)
      #pragma unroll
      for (int j = 0; j < 4; ++j) {
        float v = acc[m][n][j] * scale;
        v = v > 0.0f ? v : 0.0f;
        Cp[(size_t)(crow0 + m * 16 + j) * N + (ccol0 + n * 16)] = f32_bf16_rne(v);
      }
}

// ---------------- 128x128 m97-structure GEMM (readout only) ------------------
__global__ __launch_bounds__(256)
void gemm_bt_f32(const unsigned short* __restrict__ A,
                 const unsigned short* __restrict__ B,
                 float* __restrict__ C, int N, int K, float scale) {
  __shared__ __bf16 As[128 * 32] __attribute__((aligned(16)));
  __shared__ __bf16 Bs[128 * 32] __attribute__((aligned(16)));

  const int tid  = threadIdx.x;
  const int lane = tid & 63;
  const int wave = tid >> 6;
  const int wr   = wave >> 1, wc = wave & 1;
  const int l16  = lane & 15, kgrp = lane >> 4;

  const int brow0 = blockIdx.y * 128;
  const int bcol0 = blockIdx.x * 128;

  const int offb  = wave * 2048 + lane * 16;
  const int srow  = offb >> 6;
  const int selem = (offb & 63) >> 1;
  const unsigned short* gA0 = A + (size_t)(brow0 + srow) * K + selem;
  const unsigned short* gA1 = A + (size_t)(brow0 + srow + 16) * K + selem;
  const unsigned short* gB0 = B + (size_t)(bcol0 + srow) * K + selem;
  const unsigned short* gB1 = B + (size_t)(bcol0 + srow + 16) * K + selem;
  __bf16* lA0 = &As[wave * 1024];
  __bf16* lA1 = &As[wave * 1024 + 512];
  __bf16* lB0 = &Bs[wave * 1024];
  __bf16* lB1 = &Bs[wave * 1024 + 512];

  f32x4 acc[4][4] = {};
  const int aoff = (wr * 64 + l16) * 32 + kgrp * 8;
  const int boff = (wc * 64 + l16) * 32 + kgrp * 8;

  for (int k0 = 0; k0 < K; k0 += 32) {
    GLOAD(gA0 + k0, lA0);
    GLOAD(gA1 + k0, lA1);
    GLOAD(gB0 + k0, lB0);
    GLOAD(gB1 + k0, lB1);
    asm volatile("s_waitcnt vmcnt(0)" ::: "memory");
    __syncthreads();

    bf16x8 af[4], bfv[4];
    #pragma unroll
    for (int m = 0; m < 4; ++m)
      af[m] = *(const bf16x8*)(As + aoff + m * 16 * 32);
    #pragma unroll
    for (int n = 0; n < 4; ++n)
      bfv[n] = *(const bf16x8*)(Bs + boff + n * 16 * 32);
    #pragma unroll
    for (int m = 0; m < 4; ++m)
      #pragma unroll
      for (int n = 0; n < 4; ++n)
        acc[m][n] = MFMA16(af[m], bfv[n], acc[m][n], 0, 0, 0);
    __syncthreads();
  }

  const int crow0 = brow0 + wr * 64 + kgrp * 4;
  const int ccol0 = bcol0 + wc * 64 + l16;
  #pragma unroll
  for (int m = 0; m < 4; ++m)
    #pragma unroll
    for (int n = 0; n < 4; ++n)
      #pragma unroll
      for (int j = 0; j < 4; ++j)
        C[(size_t)(crow0 + m * 16 + j) * N + (ccol0 + n * 16)] =
            acc[m][n][j] * scale;
}

extern "C" void kernel_launch(void* const* d_in, const int* in_sizes, int n_in,
                              void* d_out, int out_size, void* d_ws, size_t ws_size,
                              hipStream_t stream) {
  const float* x    = (const float*)d_in[0];  // (4096, 2048)
  const float* W    = (const float*)d_in[1];  // (8, 2048, 2048)
  const float* beta = (const float*)d_in[2];  // (2048, 1024)
  float* out = (float*)d_out;                 // (4096, 1024) f32

  const int Bn = 4096, H = 2048, L = 8, O = 1024;

  // ws layout (bf16 as ushort): y0 | y1 | Wb[8 layers] | betaT  = 105 MB
  unsigned short* y0    = (unsigned short*)d_ws;
  unsigned short* y1    = y0 + (size_t)Bn * H;
  unsigned short* Wb    = y1 + (size_t)Bn * H;
  unsigned short* betaT = Wb + (size_t)L * H * H;

  // all 8 W layers -> bf16 in ONE kernel
  {
    int n8 = L * H * H / 8;
    cvt_f32_bf16<<<2048, 256, 0, stream>>>(W, Wb, n8);
  }
  // x -> bf16
  {
    int n8 = Bn * H / 8;
    int grid = (n8 + 255) / 256;
    if (grid > 2048) grid = 2048;
    cvt_f32_bf16<<<grid, 256, 0, stream>>>(x, y0, n8);
  }
  cvt_transpose<<<dim3(O / 32, H / 32), 256, 0, stream>>>(beta, betaT, H, O);

  const float s1 = 0.02209708691207961f;  // 1/sqrt(2048)
  unsigned short* yin = y0;
  unsigned short* yout = y1;
  for (int l = 0; l < L; ++l) {
    gemm128x256r<<<dim3(H / 256, Bn / 128), 512, 0, stream>>>(
        yin, Wb + (size_t)l * H * H, yout, H, H, s1);
    unsigned short* t = yin; yin = yout; yout = t;
  }
  gemm_bt_f32<<<dim3(O / 128, Bn / 128), 256, 0, stream>>>(yin, betaT, out, O, H,
                                                           1.0f / 2048.0f);
}

// Round 8
// 532.215 us; speedup vs baseline: 1.3243x; 1.3243x over previous
//
#include <hip/hip_runtime.h>
#include <cstdint>
#include <cstddef>

typedef __bf16          bf16x8  __attribute__((ext_vector_type(8)));
typedef float           f32x4   __attribute__((ext_vector_type(4)));
typedef unsigned short  u16x8   __attribute__((ext_vector_type(8)));

__device__ __forceinline__ unsigned short f32_bf16_rne(float f) {
  union { float f; unsigned u; } v; v.f = f;
  unsigned u = v.u + 0x7FFFu + ((v.u >> 16) & 1u);
  return (unsigned short)(u >> 16);
}

// ---------------- flat fp32 -> bf16 convert (vectorized, G13) ----------------
__global__ void cvt_f32_bf16(const float* __restrict__ in,
                             unsigned short* __restrict__ out, int n8) {
  int idx = blockIdx.x * 256 + threadIdx.x;
  int stride = gridDim.x * 256;
  for (int i = idx; i < n8; i += stride) {
    float4 a = ((const float4*)in)[2 * (size_t)i];
    float4 b = ((const float4*)in)[2 * (size_t)i + 1];
    u16x8 o;
    o[0] = f32_bf16_rne(a.x); o[1] = f32_bf16_rne(a.y);
    o[2] = f32_bf16_rne(a.z); o[3] = f32_bf16_rne(a.w);
    o[4] = f32_bf16_rne(b.x); o[5] = f32_bf16_rne(b.y);
    o[6] = f32_bf16_rne(b.z); o[7] = f32_bf16_rne(b.w);
    *(u16x8*)(out + (size_t)i * 8) = o;
  }
}

// ------------- beta (H x O, f32) -> betaT (O x H, bf16) transpose ------------
__global__ void cvt_transpose(const float* __restrict__ in,
                              unsigned short* __restrict__ out, int H, int O) {
  __shared__ float tile[32][33];
  int o0 = blockIdx.x * 32, h0 = blockIdx.y * 32;
  int tx = threadIdx.x & 31, ty = threadIdx.x >> 5;
  #pragma unroll
  for (int i = ty; i < 32; i += 8)
    tile[i][tx] = in[(size_t)(h0 + i) * O + (o0 + tx)];
  __syncthreads();
  #pragma unroll
  for (int i = ty; i < 32; i += 8)
    out[(size_t)(o0 + i) * H + (h0 + tx)] = f32_bf16_rne(tile[tx][i]);
}

#define GLOAD(gp, lp)                                                   \
  __builtin_amdgcn_global_load_lds(                                     \
      (const __attribute__((address_space(1))) void*)(gp),              \
      (__attribute__((address_space(3))) void*)(lp), 16, 0, 0)

#define MFMA16 __builtin_amdgcn_mfma_f32_16x16x32_bf16

// ============= 256x128 4-wave GEMM, per-wave 128x64 (m201 wave shape) ========
// C[m,n] = relu(scale * sum_k A[m,k]*B[n,k]) -> bf16.   A: MxK, B: NxK bf16.
// BM=256 BN=128 BK=32; 4 waves (2M x 2N), per-wave 128x64 = 8x4 16x16 frags.
// Per block-K-tile: 128 MFMA (~620cy) vs 48 ds_read_b128 (~580cy) — balanced
// (R3's 64x64 wave shape was 1240 vs ~1930, LDS-read-bound).
// LDS: 3 slots x (16KB A + 8KB B) = 72 KiB -> 2 blocks/CU (TLP preserved).
// Swizzle (64-B rows): chunk c = kgrp ^ ((row>>1)&3) spreads a frag-read's 16
// rows over all 8 bank-quads (2 lanes/quad = free, m136); applied BOTH sides
// (rule 21): staging pre-swizzles the global col, ds_read XORs the chunk.
// Since all frag row-bases are multiples of 16, (row>>1)&3 == (l16>>1)&3.
// Sync skeleton = R3's (proven race-free): per body: stage(t+2) -> slot t%3;
// lgkm(0)+vmcnt(6); barrier; read frags(t+1) [reg-dbuf]; MFMA(t).
// vmcnt: 6 gloads/stage; after staging t+2 in-flight = {t+1,t+2} = 12 ->
// vmcnt(6) completes t+1.  WAR on slot t%3: its tile t-1 frags were read in
// body t-2 and lgkm(0)-drained before barrier(t-1) < our stage issue.

#define BODY(T, FAC, FBC, FAN, FBN)                                       \
  do {                                                                    \
    const int t_ = (T);                                                   \
    if (t_ + 2 < NT) {                                                    \
      const size_t ko = (size_t)(t_ + 2) * 32;                            \
      __bf16* dA = As + sst * 8192;                                       \
      __bf16* dB = Bs + sst * 4096;                                       \
      GLOAD(gA0 + ko, dA + 0 * 2048 + tid * 8);                           \
      GLOAD(gA1 + ko, dA + 1 * 2048 + tid * 8);                           \
      GLOAD(gA2 + ko, dA + 2 * 2048 + tid * 8);                           \
      GLOAD(gA3 + ko, dA + 3 * 2048 + tid * 8);                           \
      GLOAD(gB0 + ko, dB + 0 * 2048 + tid * 8);                           \
      GLOAD(gB1 + ko, dB + 1 * 2048 + tid * 8);                           \
      asm volatile("s_waitcnt lgkmcnt(0)" ::: "memory");                  \
      asm volatile("s_waitcnt vmcnt(6)" ::: "memory");                    \
    } else {                                                              \
      asm volatile("s_waitcnt lgkmcnt(0)" ::: "memory");                  \
      asm volatile("s_waitcnt vmcnt(0)" ::: "memory");                    \
    }                                                                     \
    __builtin_amdgcn_s_barrier();                                         \
    __builtin_amdgcn_sched_barrier(0);                                    \
    if (t_ + 1 < NT) {                                                    \
      const __bf16* rA = As + srd * 8192;                                 \
      const __bf16* rB = Bs + srd * 4096;                                 \
      _Pragma("unroll")                                                   \
      for (int m = 0; m < 8; ++m)                                         \
        FAN[m] = *(const bf16x8*)(rA + (m * 16 + l16) * 32 + cswz);       \
      _Pragma("unroll")                                                   \
      for (int n = 0; n < 4; ++n)                                         \
        FBN[n] = *(const bf16x8*)(rB + (bRow + n * 16) * 32 + cswz);      \
    }                                                                     \
    __builtin_amdgcn_s_setprio(1);                                        \
    _Pragma("unroll")                                                     \
    for (int m = 0; m < 8; ++m)                                           \
      _Pragma("unroll")                                                   \
      for (int n = 0; n < 4; ++n)                                         \
        acc[m][n] = MFMA16(FAC[m], FBC[n], acc[m][n], 0, 0, 0);           \
    __builtin_amdgcn_s_setprio(0);                                        \
    sst = sst + 1 == 3 ? 0 : sst + 1;                                     \
    srd = srd + 1 == 3 ? 0 : srd + 1;                                     \
  } while (0)

__global__ __launch_bounds__(256, 2)
void gemm256x128w(const unsigned short* __restrict__ A,
                  const unsigned short* __restrict__ B,
                  unsigned short* __restrict__ Cp, int N, int K, float scale) {
  __shared__ __bf16 As[3 * 256 * 32] __attribute__((aligned(16)));  // 48 KiB
  __shared__ __bf16 Bs[3 * 128 * 32] __attribute__((aligned(16)));  // 24 KiB

  const int tid  = threadIdx.x;
  const int lane = tid & 63;
  const int wave = tid >> 6;      // 0..3
  const int wr   = wave >> 1;     // 0..1 (M half)
  const int wcN  = wave & 1;      // 0..1 (N half)
  const int l16  = lane & 15;
  const int kgrp = lane >> 4;     // 0..3

  const int brow0 = blockIdx.y * 256;
  const int bcol0 = blockIdx.x * 128;   // grid 16x16; XCD = (y*16+x)%8 = x%8

  // ds_read swizzled chunk: uniform across frags since bases are mult of 16
  const int cswz = ((kgrp ^ ((l16 >> 1) & 3)) << 3);
  const int bRow = wcN * 64;
  // A frag rows: wr*128 + m*16 + l16  (handled inside BODY via rA offset)
  const __bf16* As_wr = nullptr; (void)As_wr;

  // staging: thread covers row srow = tid>>2 (per 64-row g-block), chunk
  // tid&3; global col pre-swizzled so swizzled ds_read sees logical data.
  const int srow = tid >> 2;                                   // 0..63
  const int scol = (((tid & 3) ^ ((srow >> 1) & 3)) << 3);     // elements
  const unsigned short* gA0 = A + (size_t)(brow0 +   0 + srow) * K + scol;
  const unsigned short* gA1 = A + (size_t)(brow0 +  64 + srow) * K + scol;
  const unsigned short* gA2 = A + (size_t)(brow0 + 128 + srow) * K + scol;
  const unsigned short* gA3 = A + (size_t)(brow0 + 192 + srow) * K + scol;
  const unsigned short* gB0 = B + (size_t)(bcol0 +   0 + srow) * K + scol;
  const unsigned short* gB1 = B + (size_t)(bcol0 +  64 + srow) * K + scol;

  f32x4  acc[8][4] = {};
  bf16x8 fa0[8], fb0[4], fa1[8], fb1[4];

  const int NT = K >> 5;  // 64 for K=2048 (assumes NT even, >= 4)

  // ---- prologue: stage tiles 0,1 -> slots 0,1; wait tile0; read its frags
  {
    GLOAD(gA0, &As[0 * 2048 + tid * 8]);
    GLOAD(gA1, &As[1 * 2048 + tid * 8]);
    GLOAD(gA2, &As[2 * 2048 + tid * 8]);
    GLOAD(gA3, &As[3 * 2048 + tid * 8]);
    GLOAD(gB0, &Bs[0 * 2048 + tid * 8]);
    GLOAD(gB1, &Bs[1 * 2048 + tid * 8]);
    GLOAD(gA0 + 32, &As[8192 + 0 * 2048 + tid * 8]);
    GLOAD(gA1 + 32, &As[8192 + 1 * 2048 + tid * 8]);
    GLOAD(gA2 + 32, &As[8192 + 2 * 2048 + tid * 8]);
    GLOAD(gA3 + 32, &As[8192 + 3 * 2048 + tid * 8]);
    GLOAD(gB0 + 32, &Bs[4096 + 0 * 2048 + tid * 8]);
    GLOAD(gB1 + 32, &Bs[4096 + 1 * 2048 + tid * 8]);
    asm volatile("s_waitcnt vmcnt(6)" ::: "memory");
    __builtin_amdgcn_s_barrier();
    const __bf16* rA = As + (size_t)wr * 0;  // slot 0
    #pragma unroll
    for (int m = 0; m < 8; ++m)
      fa0[m] = *(const bf16x8*)(As + ((wr * 128 + m * 16 + l16) * 32) + cswz);
    #pragma unroll
    for (int n = 0; n < 4; ++n)
      fb0[n] = *(const bf16x8*)(Bs + ((bRow + n * 16 + l16) * 32) + cswz);
    (void)rA;
  }

  // NOTE: BODY reads A rows as (m*16 + l16) relative to rA; fold wr there:
  // rA base includes wr*128 rows.
  int sst = 2, srd = 1;
  {
    // adjust: BODY uses rA + (m*16+l16)*32; add wr offset via pointer bases
  }
  const int aWrOff = wr * 128 * 32;  // element offset of this wave's A half
  // Re-wrap BODY pointer math: rA passed as As + srd*8192 + aWrOff, and the
  // B frag rows already include bRow + l16 via (bRow + n*16) + l16:
  // we fold l16 into bRow-style below by using same formula as prologue.
  #define RDFRAGS(FAN, FBN)                                               \
    do {                                                                  \
      const __bf16* rA = As + srd * 8192 + aWrOff;                        \
      const __bf16* rB = Bs + srd * 4096;                                 \
      _Pragma("unroll")                                                   \
      for (int m = 0; m < 8; ++m)                                         \
        FAN[m] = *(const bf16x8*)(rA + (m * 16 + l16) * 32 + cswz);       \
      _Pragma("unroll")                                                   \
      for (int n = 0; n < 4; ++n)                                         \
        FBN[n] = *(const bf16x8*)(rB + (bRow + n * 16 + l16) * 32 + cswz);\
    } while (0)

  #define BODY2(T, FAC, FBC, FAN, FBN)                                    \
    do {                                                                  \
      const int t_ = (T);                                                 \
      if (t_ + 2 < NT) {                                                  \
        const size_t ko = (size_t)(t_ + 2) * 32;                          \
        __bf16* dA = As + sst * 8192;                                     \
        __bf16* dB = Bs + sst * 4096;                                     \
        GLOAD(gA0 + ko, dA + 0 * 2048 + tid * 8);                         \
        GLOAD(gA1 + ko, dA + 1 * 2048 + tid * 8);                         \
        GLOAD(gA2 + ko, dA + 2 * 2048 + tid * 8);                         \
        GLOAD(gA3 + ko, dA + 3 * 2048 + tid * 8);                         \
        GLOAD(gB0 + ko, dB + 0 * 2048 + tid * 8);                         \
        GLOAD(gB1 + ko, dB + 1 * 2048 + tid * 8);                         \
        asm volatile("s_waitcnt lgkmcnt(0)" ::: "memory");                \
        asm volatile("s_waitcnt vmcnt(6)" ::: "memory");                  \
      } else {                                                            \
        asm volatile("s_waitcnt lgkmcnt(0)" ::: "memory");                \
        asm volatile("s_waitcnt vmcnt(0)" ::: "memory");                  \
      }                                                                   \
      __builtin_amdgcn_s_barrier();                                       \
      __builtin_amdgcn_sched_barrier(0);                                  \
      if (t_ + 1 < NT) RDFRAGS(FAN, FBN);                                 \
      __builtin_amdgcn_s_setprio(1);                                      \
      _Pragma("unroll")                                                   \
      for (int m = 0; m < 8; ++m)                                         \
        _Pragma("unroll")                                                 \
        for (int n = 0; n < 4; ++n)                                       \
          acc[m][n] = MFMA16(FAC[m], FBC[n], acc[m][n], 0, 0, 0);         \
      __builtin_amdgcn_s_setprio(0);                                      \
      sst = sst + 1 == 3 ? 0 : sst + 1;                                   \
      srd = srd + 1 == 3 ? 0 : srd + 1;                                   \
    } while (0)

  // fix prologue A-read to this wave's half (redo with aWrOff)
  #pragma unroll
  for (int m = 0; m < 8; ++m)
    fa0[m] = *(const bf16x8*)(As + aWrOff + (m * 16 + l16) * 32 + cswz);

  for (int t = 0; t < NT; t += 2) {
    BODY2(t,     fa0, fb0, fa1, fb1);
    BODY2(t + 1, fa1, fb1, fa0, fb0);
  }

  // epilogue: relu(acc*scale) -> bf16. D: col=lane&15, row=(lane>>4)*4+j
  const int crow0 = brow0 + wr * 128 + kgrp * 4;
  const int ccol0 = bcol0 + wcN * 64 + l16;
  #pragma unroll
  for (int m = 0; m < 8; ++m)
    #pragma unroll
    for (int n = 0; n < 4; ++n)
      #pragma unroll
      for (int j = 0; j < 4; ++j) {
        float v = acc[m][n][j] * scale;
        v = v > 0.0f ? v : 0.0f;
        Cp[(size_t)(crow0 + m * 16 + j) * N + (ccol0 + n * 16)] = f32_bf16_rne(v);
      }
}

// ---------------- 128x128 m97-structure GEMM (readout only) ------------------
__global__ __launch_bounds__(256)
void gemm_bt_f32(const unsigned short* __restrict__ A,
                 const unsigned short* __restrict__ B,
                 float* __restrict__ C, int N, int K, float scale) {
  __shared__ __bf16 As[128 * 32] __attribute__((aligned(16)));
  __shared__ __bf16 Bs[128 * 32] __attribute__((aligned(16)));

  const int tid  = threadIdx.x;
  const int lane = tid & 63;
  const int wave = tid >> 6;
  const int wr   = wave >> 1, wc = wave & 1;
  const int l16  = lane & 15, kgrp = lane >> 4;

  const int brow0 = blockIdx.y * 128;
  const int bcol0 = blockIdx.x * 128;

  const int offb  = wave * 2048 + lane * 16;
  const int srow  = offb >> 6;
  const int selem = (offb & 63) >> 1;
  const unsigned short* gA0 = A + (size_t)(brow0 + srow) * K + selem;
  const unsigned short* gA1 = A + (size_t)(brow0 + srow + 16) * K + selem;
  const unsigned short* gB0 = B + (size_t)(bcol0 + srow) * K + selem;
  const unsigned short* gB1 = B + (size_t)(bcol0 + srow + 16) * K + selem;
  __bf16* lA0 = &As[wave * 1024];
  __bf16* lA1 = &As[wave * 1024 + 512];
  __bf16* lB0 = &Bs[wave * 1024];
  __bf16* lB1 = &Bs[wave * 1024 + 512];

  f32x4 acc[4][4] = {};
  const int aoff = (wr * 64 + l16) * 32 + kgrp * 8;
  const int boff = (wc * 64 + l16) * 32 + kgrp * 8;

  for (int k0 = 0; k0 < K; k0 += 32) {
    GLOAD(gA0 + k0, lA0);
    GLOAD(gA1 + k0, lA1);
    GLOAD(gB0 + k0, lB0);
    GLOAD(gB1 + k0, lB1);
    asm volatile("s_waitcnt vmcnt(0)" ::: "memory");
    __syncthreads();

    bf16x8 af[4], bfv[4];
    #pragma unroll
    for (int m = 0; m < 4; ++m)
      af[m] = *(const bf16x8*)(As + aoff + m * 16 * 32);
    #pragma unroll
    for (int n = 0; n < 4; ++n)
      bfv[n] = *(const bf16x8*)(Bs + boff + n * 16 * 32);
    #pragma unroll
    for (int m = 0; m < 4; ++m)
      #pragma unroll
      for (int n = 0; n < 4; ++n)
        acc[m][n] = MFMA16(af[m], bfv[n], acc[m][n], 0, 0, 0);
    __syncthreads();
  }

  const int crow0 = brow0 + wr * 64 + kgrp * 4;
  const int ccol0 = bcol0 + wc * 64 + l16;
  #pragma unroll
  for (int m = 0; m < 4; ++m)
    #pragma unroll
    for (int n = 0; n < 4; ++n)
      #pragma unroll
      for (int j = 0; j < 4; ++j)
        C[(size_t)(crow0 + m * 16 + j) * N + (ccol0 + n * 16)] =
            acc[m][n][j] * scale;
}

extern "C" void kernel_launch(void* const* d_in, const int* in_sizes, int n_in,
                              void* d_out, int out_size, void* d_ws, size_t ws_size,
                              hipStream_t stream) {
  const float* x    = (const float*)d_in[0];  // (4096, 2048)
  const float* W    = (const float*)d_in[1];  // (8, 2048, 2048)
  const float* beta = (const float*)d_in[2];  // (2048, 1024)
  float* out = (float*)d_out;                 // (4096, 1024) f32

  const int Bn = 4096, H = 2048, L = 8, O = 1024;

  // ws layout (bf16 as ushort): y0 | y1 | Wb[8 layers] | betaT  = 105 MB
  unsigned short* y0    = (unsigned short*)d_ws;
  unsigned short* y1    = y0 + (size_t)Bn * H;
  unsigned short* Wb    = y1 + (size_t)Bn * H;
  unsigned short* betaT = Wb + (size_t)L * H * H;

  // all 8 W layers -> bf16 in ONE kernel
  {
    int n8 = L * H * H / 8;
    cvt_f32_bf16<<<2048, 256, 0, stream>>>(W, Wb, n8);
  }
  // x -> bf16
  {
    int n8 = Bn * H / 8;
    int grid = (n8 + 255) / 256;
    if (grid > 2048) grid = 2048;
    cvt_f32_bf16<<<grid, 256, 0, stream>>>(x, y0, n8);
  }
  cvt_transpose<<<dim3(O / 32, H / 32), 256, 0, stream>>>(beta, betaT, H, O);

  const float s1 = 0.02209708691207961f;  // 1/sqrt(2048)
  unsigned short* yin = y0;
  unsigned short* yout = y1;
  for (int l = 0; l < L; ++l) {
    gemm256x128w<<<dim3(H / 128, Bn / 256), 256, 0, stream>>>(
        yin, Wb + (size_t)l * H * H, yout, H, H, s1);
    unsigned short* t = yin; yin = yout; yout = t;
  }
  gemm_bt_f32<<<dim3(O / 128, Bn / 128), 256, 0, stream>>>(yin, betaT, out, O, H,
                                                           1.0f / 2048.0f);
}